// Round 1
// baseline (144.498 us; speedup 1.0000x reference)
//
#include <hip/hip_runtime.h>
#include <hip/hip_bf16.h>

#define N_RAW  100000
#define DIM    256
#define OUTD   128
#define KN     10
#define N1N    40960
#define BATCH  4096

typedef __attribute__((ext_vector_type(8))) short bf16x8;
typedef __attribute__((ext_vector_type(4))) float f32x4;

// ---- convert W1/W2 to bf16 ----
__global__ void cvt_weights(const float* __restrict__ W1, const float* __restrict__ W2,
                            __hip_bfloat16* __restrict__ W1b, __hip_bfloat16* __restrict__ W2b) {
  int i = blockIdx.x * blockDim.x + threadIdx.x;
  if (i < OUTD * 2 * DIM)  W1b[i] = __float2bfloat16(W1[i]);
  if (i < OUTD * 2 * OUTD) W2b[i] = __float2bfloat16(W2[i]);
}

// ---- X1[i] = [ raw[nodes1[i]] | mean_k raw[neighs1[i,k]] ]  (bf16 [N1, 512]) ----
__global__ void build_x1(const float* __restrict__ raw, const int* __restrict__ nodes1,
                         const int* __restrict__ neighs1, __hip_bfloat16* __restrict__ X1) {
  int i = blockIdx.x;        // node row
  int c = threadIdx.x;       // 0..255 feature column
  float s = 0.f;
#pragma unroll
  for (int k = 0; k < KN; ++k) {
    s += raw[(size_t)neighs1[i * KN + k] * DIM + c];
  }
  X1[(size_t)i * (2 * DIM) + c]       = __float2bfloat16(raw[(size_t)nodes1[i] * DIM + c]);
  X1[(size_t)i * (2 * DIM) + DIM + c] = __float2bfloat16(s * 0.1f);
}

// ---- X2[i] = [ h1[map2[i]] | mean_k h1[neighs2[i,k]] ]  (bf16 [B, 256]) ----
__global__ void build_x2(const __hip_bfloat16* __restrict__ h1, const int* __restrict__ map2,
                         const int* __restrict__ neighs2, __hip_bfloat16* __restrict__ X2) {
  int i = blockIdx.x;        // batch row
  int c = threadIdx.x;       // 0..127
  float s = 0.f;
#pragma unroll
  for (int k = 0; k < KN; ++k) {
    s += __bfloat162float(h1[(size_t)neighs2[i * KN + k] * OUTD + c]);
  }
  X2[(size_t)i * (2 * OUTD) + c]        = h1[(size_t)map2[i] * OUTD + c];
  X2[(size_t)i * (2 * OUTD) + OUTD + c] = __float2bfloat16(s * 0.1f);
}

// ---- H = relu(X[M,K] @ W[128,K]^T); out bf16 and/or f32 ----
// 4 waves/block, wave w computes rows m0..m0+15 (m0 = blk*64 + w*16), all 128 cols.
// mfma_f32_16x16x32_bf16 layouts (m89/m91-verified):
//   A frag: row = lane&15, k = (lane>>4)*8 + j   (contiguous 16B from X row)
//   B frag: col = lane&15, k = (lane>>4)*8 + j   (contiguous 16B from W row)
//   D frag: col = lane&15, row = (lane>>4)*4 + j
template <int K>
__global__ void gemm_relu(const __hip_bfloat16* __restrict__ X, const __hip_bfloat16* __restrict__ W,
                          __hip_bfloat16* __restrict__ outB, float* __restrict__ outF) {
  const short* Xs = (const short*)X;
  const short* Ws = (const short*)W;
  int wave = threadIdx.x >> 6;
  int lane = threadIdx.x & 63;
  int m0 = blockIdx.x * 64 + wave * 16;
  int r16 = lane & 15;
  int kg  = lane >> 4;   // 0..3

  f32x4 acc[8];
#pragma unroll
  for (int n = 0; n < 8; ++n) acc[n] = (f32x4){0.f, 0.f, 0.f, 0.f};

  const short* xrow = Xs + (size_t)(m0 + r16) * K + kg * 8;
#pragma unroll 4
  for (int k = 0; k < K; k += 32) {
    bf16x8 a = *(const bf16x8*)(xrow + k);
#pragma unroll
    for (int n = 0; n < 8; ++n) {
      bf16x8 b = *(const bf16x8*)(Ws + (size_t)(n * 16 + r16) * K + k + kg * 8);
      acc[n] = __builtin_amdgcn_mfma_f32_16x16x32_bf16(a, b, acc[n], 0, 0, 0);
    }
  }

#pragma unroll
  for (int n = 0; n < 8; ++n) {
#pragma unroll
    for (int j = 0; j < 4; ++j) {
      int r = m0 + kg * 4 + j;
      int c = n * 16 + r16;
      float v = fmaxf(acc[n][j], 0.f);
      if (outB) outB[(size_t)r * OUTD + c] = __float2bfloat16(v);
      if (outF) outF[(size_t)r * OUTD + c] = v;
    }
  }
}

extern "C" void kernel_launch(void* const* d_in, const int* in_sizes, int n_in,
                              void* d_out, int out_size, void* d_ws, size_t ws_size,
                              hipStream_t stream) {
  const float* raw     = (const float*)d_in[0];
  const float* W1      = (const float*)d_in[1];
  const float* W2      = (const float*)d_in[2];
  const int*   nodes1  = (const int*)d_in[3];
  const int*   neighs1 = (const int*)d_in[4];
  const int*   map2    = (const int*)d_in[5];
  const int*   neighs2 = (const int*)d_in[6];
  float* out = (float*)d_out;

  char* ws = (char*)d_ws;
  // workspace layout (256B-aligned offsets), total ~52.2 MB
  __hip_bfloat16* X1  = (__hip_bfloat16*)(ws);                 // 40960*512*2 = 41943040
  __hip_bfloat16* h1  = (__hip_bfloat16*)(ws + 41943040);      // 40960*128*2 = 10485760
  __hip_bfloat16* X2  = (__hip_bfloat16*)(ws + 52428800);      //  4096*256*2 =  2097152
  __hip_bfloat16* W1b = (__hip_bfloat16*)(ws + 54525952);      //   128*512*2 =   131072
  __hip_bfloat16* W2b = (__hip_bfloat16*)(ws + 54657024);      //   128*256*2 =    65536

  cvt_weights<<<256, 256, 0, stream>>>(W1, W2, W1b, W2b);
  build_x1<<<N1N, 256, 0, stream>>>(raw, nodes1, neighs1, X1);
  gemm_relu<2 * DIM><<<N1N / 64, 256, 0, stream>>>(X1, W1b, h1, nullptr);
  build_x2<<<BATCH, OUTD, 0, stream>>>(h1, map2, neighs2, X2);
  gemm_relu<2 * OUTD><<<BATCH / 64, 256, 0, stream>>>(X2, W2b, nullptr, out);
}